// Round 17
// baseline (54.002 us; speedup 1.0000x reference)
//
#include <hip/hip_runtime.h>
#include <hip/hip_bf16.h>
#include <math.h>

#define B_ 64
#define P_ 128
#define C_ 72
#define PADC 80    // f16 global row stride for Ah
#define IT 8       // i-rows per edge block (2 per wave, ii-outer)

typedef __attribute__((ext_vector_type(8))) _Float16 half8v;
typedef __attribute__((ext_vector_type(4))) _Float16 half4v;
typedef __attribute__((ext_vector_type(4))) float f32x4;
typedef __attribute__((ext_vector_type(2))) float f32x2;

// precomputed weight-fragment table (units: half8v, 64 per fragment)
#define FRAG_WE2  0          // We2 kt=0,1 (K32), 15 frag slots
#define FRAG_WE1A (15 * 64)  // We1 rows 0..71, 15 frags
#define FRAG_WE1B (30 * 64)  // We1 rows 72..143 (+be1 @k=72), 15 frags
#define FRAG_WH1  (45 * 64)  // Wh1 (+bh1 @k=144), 25 frags
#define FRAG_WH2  (70 * 64)  // Wh2 (+bh2 @k=72), 15 frags
#define NFRAG 85             // + 5 K16-tail frags + w12p + wmwxp appended

__device__ __forceinline__ float psi_f(float v) {
    float a = fabsf(v);
    return copysignf(__logf(1.0f + a), v);
}
template <int CTRL>
__device__ __forceinline__ float dpp_add(float v) {
    int s = __builtin_amdgcn_update_dpp(0, __builtin_bit_cast(int, v), CTRL, 0xF, 0xF, true);
    return v + __builtin_bit_cast(float, s);
}
// full sum across each 16-lane group (fixed tree -> deterministic)
__device__ __forceinline__ float red16(float v) {
    v = dpp_add<0xB1>(v);    // quad_perm(1,0,3,2)
    v = dpp_add<0x4E>(v);    // quad_perm(2,3,0,1)
    v = dpp_add<0x141>(v);   // row_half_mirror
    v = dpp_add<0x140>(v);   // row_mirror
    return v;
}
__device__ __forceinline__ half8v cvt8(const float* p) {
    f32x4 a = *(const f32x4*)p;
    f32x4 b = *(const f32x4*)(p + 4);
    half8v r = {(_Float16)a[0], (_Float16)a[1], (_Float16)a[2], (_Float16)a[3],
                (_Float16)b[0], (_Float16)b[1], (_Float16)b[2], (_Float16)b[3]};
    return r;
}

// ---------------- Kernel 0: build all weight fragments ------------------
__global__ __launch_bounds__(64) void setup_kernel(
    const float* __restrict__ We1, const float* __restrict__ be1,
    const float* __restrict__ We2, const float* __restrict__ be2,
    const float* __restrict__ Wh1, const float* __restrict__ bh1,
    const float* __restrict__ Wh2, const float* __restrict__ bh2,
    const float* __restrict__ Wm, const float* __restrict__ Wx,
    half8v* __restrict__ frags)
{
    const int bid = blockIdx.x;
    const int l = threadIdx.x;
    const int c16 = l & 15, g = l >> 4;

    if (bid == NFRAG + 5) {
        // padded w144/w145 table: w12p[2][80], zeros beyond col 71
        _Float16* w12p = (_Float16*)((half4v*)(frags + NFRAG * 64) + 5 * 64);
        for (int i = l; i < 160; i += 64) {
            int s = i / 80, c = i - s * 80;
            w12p[i] = (c < C_) ? (_Float16)We1[(144 + s) * C_ + c] : (_Float16)0.f;
        }
        // packed (Wm, Wx) pair table, padded to 80
        f32x2* wmwxp = (f32x2*)(w12p + 160);
        for (int idx = l; idx < 80; idx += 64) {
            f32x2 v;
            v[0] = (idx < C_) ? Wm[idx] : 0.f;
            v[1] = (idx < C_) ? Wx[idx] : 0.f;
            wmwxp[idx] = v;
        }
        return;
    }
    if (bid >= NFRAG) {
        // K16 tail frags for edge We2: k = 64 + 4g + jj, bias(be2) at k=72
        half4v* tail = (half4v*)(frags + NFRAG * 64);
        const int nt = bid - NFRAG;
        const int n = nt * 16 + c16;
        half4v f = {};
        if (n < C_) {
            #pragma unroll
            for (int jj = 0; jj < 4; ++jj) {
                int k = 64 + 4 * g + jj;
                float w = 0.f;
                if (k < C_) w = We2[k * C_ + n];
                else if (k == C_) w = be2[n];
                f[jj] = (_Float16)w;
            }
        }
        tail[nt * 64 + l] = f;
        return;
    }

    const float* W;
    const float* bias;
    int kmax, rel;
    if (bid < 15)      { W = We2;            bias = be2;     kmax = 72;  rel = bid; }
    else if (bid < 30) { W = We1;            bias = nullptr; kmax = 72;  rel = bid - 15; }
    else if (bid < 45) { W = We1 + 72 * C_;  bias = be1;     kmax = 72;  rel = bid - 30; }
    else if (bid < 70) { W = Wh1;            bias = bh1;     kmax = 144; rel = bid - 45; }
    else               { W = Wh2;            bias = bh2;     kmax = 72;  rel = bid - 70; }
    const int kt = rel / 5, nt = rel - 5 * kt;
    const int n = nt * 16 + c16;

    half8v f = {};
    if (n < C_) {
        #pragma unroll
        for (int jj = 0; jj < 8; ++jj) {
            int k = kt * 32 + g * 8 + jj;
            float w = 0.f;
            if (k < kmax) w = W[k * C_ + n];
            else if (k == kmax && bias) w = bias[n];
            f[jj] = (_Float16)w;
        }
    }
    frags[bid * 64 + l] = f;
}

// ---------------- Kernel 1: pre (MFMA) ----------------------------------
// sel=0: A rows (row layout, bias 1.0 baked at col 72).  sel=1: Bc frags.
__global__ __launch_bounds__(64) void pre_kernel(
    const float* __restrict__ h, const half8v* __restrict__ frags,
    _Float16* __restrict__ Ah, half8v* __restrict__ Bcf,
    half4v* __restrict__ Bcft)
{
    __shared__ _Float16 T[16][88];
    const int l = threadIdx.x, c16 = l & 15, g = l >> 4;
    const int sel = blockIdx.x & 1;
    const int m0 = (blockIdx.x >> 1) * 16;

    const float* hrow = h + (m0 + c16) * C_;
    half8v a0 = cvt8(hrow + g * 8);
    half8v a1 = cvt8(hrow + 32 + g * 8);
    half8v a2 = {};
    if (g == 0) a2 = cvt8(hrow + 64);
    else if (g == 1) a2[0] = (_Float16)1.0f;   // bias row k=72

    const half8v* F = frags + (sel ? FRAG_WE1B : FRAG_WE1A);
    f32x4 acc[5] = {};
    #pragma unroll
    for (int kt = 0; kt < 3; ++kt) {
        half8v a = (kt == 0) ? a0 : (kt == 1 ? a1 : a2);
        #pragma unroll
        for (int nt = 0; nt < 5; ++nt)
            acc[nt] = __builtin_amdgcn_mfma_f32_16x16x32_f16(a, F[(kt * 5 + nt) * 64 + l], acc[nt], 0, 0, 0);
    }

    if (sel == 0) {
        #pragma unroll
        for (int nt = 0; nt < 5; ++nt) {
            int n = nt * 16 + c16;
            if (n < C_) {
                #pragma unroll
                for (int r = 0; r < 4; ++r)
                    Ah[(m0 + 4 * g + r) * PADC + n] = (_Float16)acc[nt][r];
            }
        }
        if (l < 16) {   // bake be2-bias marker: col 72 = 1.0, 73..79 = 0
            half4v one = {(_Float16)1.0f, (_Float16)0.f, (_Float16)0.f, (_Float16)0.f};
            half4v z = {};
            *(half4v*)&Ah[(m0 + l) * PADC + 72] = one;
            *(half4v*)&Ah[(m0 + l) * PADC + 76] = z;
        }
    } else {
        // D layout -> LDS -> B-fragment layout
        #pragma unroll
        for (int nt = 0; nt < 5; ++nt) {
            int n = nt * 16 + c16;
            if (n < C_) {
                #pragma unroll
                for (int r = 0; r < 4; ++r)
                    T[4 * g + r][n] = (_Float16)acc[nt][r];
            }
        }
        {   // zero pad cols 72..87
            int zr = l >> 2, zc = 72 + (l & 3) * 4;
            half4v z = {};
            *(half4v*)&T[zr][zc] = z;
        }
        __syncthreads();
        const int bb = m0 >> 7, jt = (m0 >> 4) & 7;
        half8v f0 = *(const half8v*)&T[c16][g * 8];
        half8v f1 = *(const half8v*)&T[c16][32 + g * 8];
        half4v ft = *(const half4v*)&T[c16][64 + g * 4];
        Bcf[((bb * 8 + jt) * 2 + 0) * 64 + l] = f0;
        Bcf[((bb * 8 + jt) * 2 + 1) * 64 + l] = f1;
        Bcft[(bb * 8 + jt) * 64 + l] = ft;
    }
}

// ---------------- Kernel 2: edge MLP + fused node MLP (4-wave tail) -----
__global__ __launch_bounds__(256, 2) void edge_kernel(
    const float* __restrict__ x, const float* __restrict__ h,
    const _Float16* __restrict__ Ah,
    const half8v* __restrict__ Bcf, const half4v* __restrict__ Bcft,
    const half8v* __restrict__ frags,
    const float* __restrict__ bm,
    float* __restrict__ hout, float* __restrict__ xout)
{
    __shared__ float wm_s[IT][80];          // this block's wm rows (f32)
    __shared__ _Float16 g_s[16][88];        // node GEMM1 transpose buffer

    const int b  = blockIdx.x >> 4;
    const int it = blockIdx.x & 15;
    const int t  = threadIdx.x;
    const int wv = t >> 6;
    const int l  = t & 63;
    const int c16 = l & 15;
    const int g   = l >> 4;

    // ---- We2 fragments: 2x K32 + 1x K16 tail ----
    half8v Wf[2][5];
    #pragma unroll
    for (int kt = 0; kt < 2; ++kt)
        #pragma unroll
        for (int nt = 0; nt < 5; ++nt)
            Wf[kt][nt] = frags[FRAG_WE2 + (kt * 5 + nt) * 64 + l];
    half4v Wf2[5];
    const half4v* tail = (const half4v*)(frags + NFRAG * 64);
    #pragma unroll
    for (int nt = 0; nt < 5; ++nt)
        Wf2[nt] = tail[nt * 64 + l];

    // padded w144/w145 table
    const _Float16* w12p = (const _Float16*)(tail + 5 * 64);
    half8v w1a = *(const half8v*)&w12p[g * 8];
    half8v w1b = *(const half8v*)&w12p[32 + g * 8];
    half4v w1t = *(const half4v*)&w12p[64 + g * 4];
    half8v w2a = *(const half8v*)&w12p[80 + g * 8];
    half8v w2b = *(const half8v*)&w12p[80 + 32 + g * 8];
    half4v w2t = *(const half4v*)&w12p[80 + 64 + g * 4];

    // packed (Wm,Wx) pairs: 10 vector loads instead of 40 scalar
    const f32x2* wmwxp = (const f32x2*)(w12p + 160);
    f32x2 WmWx[5][4];
    #pragma unroll
    for (int nt = 0; nt < 5; ++nt) {
        f32x4 p0 = *(const f32x4*)&wmwxp[nt * 16 + 4 * g];
        f32x4 p1 = *(const f32x4*)&wmwxp[nt * 16 + 4 * g + 2];
        WmWx[nt][0][0] = p0[0]; WmWx[nt][0][1] = p0[1];
        WmWx[nt][1][0] = p0[2]; WmWx[nt][1][1] = p0[3];
        WmWx[nt][2][0] = p1[0]; WmWx[nt][2][1] = p1[1];
        WmWx[nt][3][0] = p1[2]; WmWx[nt][3][1] = p1[3];
    }
    const float bm0 = bm[0];
    const f32x4 zero4 = {0.f, 0.f, 0.f, 0.f};

    const half8v* Bb = Bcf + (size_t)(b * 8) * 2 * 64;
    const half4v* Bt = Bcft + (size_t)(b * 8) * 64;
    const float*  xb = x + b * P_ * 4;
    const int c16_4 = c16 << 2;
    const int m0row = b * P_ + it * IT;

    #pragma unroll 1
    for (int ii = 0; ii < 2; ++ii) {
        const int rowl = wv * 2 + ii;
        const int node_i = m0row + rowl;
        const f32x4 xi = *(const f32x4*)&x[node_i * 4];
        const _Float16* Arow = Ah + node_i * PADC;
        half8v a0 = *(const half8v*)&Arow[g * 8];
        half8v a1 = *(const half8v*)&Arow[32 + g * 8];
        half4v at = *(const half4v*)&Arow[64 + g * 4];   // g=2 carries baked bias

        // Bc prefetch, 1-deep
        half8v bc0 = Bb[l];
        half8v bc1 = Bb[64 + l];
        half4v bct = Bt[l];

        f32x4 wmacc[5] = {};
        f32x4 xacc = {0.f, 0.f, 0.f, 0.f};

        #pragma unroll 1
        for (int q = 0; q < 2; ++q) {
            // ---- 64-edge geometry + psi, computed ONCE per 4 tiles ----
            f32x4 xjq = *(const f32x4*)&xb[(q * 64 + l) * 4];
            float d0 = xi[0] - xjq[0], d1 = xi[1] - xjq[1];
            float d2 = xi[2] - xjq[2], d3 = xi[3] - xjq[3];
            float nn = d0 * d0 - d1 * d1 - d2 * d2 - d3 * d3;
            float pp = xi[0] * xjq[0] - xi[1] * xjq[1] - xi[2] * xjq[2] - xi[3] * xjq[3];
            unsigned geo =
                (unsigned)__builtin_bit_cast(unsigned short, (_Float16)psi_f(nn)) |
                ((unsigned)__builtin_bit_cast(unsigned short, (_Float16)psi_f(pp)) << 16);
            int geo0 = __builtin_amdgcn_ds_bpermute(c16_4,       (int)geo);
            int geo1 = __builtin_amdgcn_ds_bpermute(c16_4 + 64,  (int)geo);
            int geo2 = __builtin_amdgcn_ds_bpermute(c16_4 + 128, (int)geo);
            int geo3 = __builtin_amdgcn_ds_bpermute(c16_4 + 192, (int)geo);

            #pragma unroll
            for (int s = 0; s < 4; ++s) {
                const int jt = q * 4 + s;
                const int njt = (jt + 1) & 7;
                half8v nbc0 = Bb[(njt * 2) * 64 + l];
                half8v nbc1 = Bb[(njt * 2 + 1) * 64 + l];
                half4v nbct = Bt[njt * 64 + l];
                f32x4 xjv = *(const f32x4*)&xb[(jt * 16 + c16) * 4];

                int geos = (s == 0) ? geo0 : (s == 1) ? geo1 : (s == 2) ? geo2 : geo3;
                _Float16 nh = __builtin_bit_cast(_Float16, (unsigned short)((unsigned)geos & 0xFFFFu));
                _Float16 ph = __builtin_bit_cast(_Float16, (unsigned short)((unsigned)geos >> 16));
                half8v n8 = {nh, nh, nh, nh, nh, nh, nh, nh};
                half8v p8 = {ph, ph, ph, ph, ph, ph, ph, ph};
                half4v n4 = {nh, nh, nh, nh};
                half4v p4 = {ph, ph, ph, ph};
                half8v zero8 = {};
                half4v zero4h = {};

                // ---- phase A: m1^T fragments (branch-free tail) ----
                half8v v0 = a0 + bc0;
                v0 = __builtin_elementwise_fma(w1a, n8, v0);
                v0 = __builtin_elementwise_fma(w2a, p8, v0);
                half8v af0 = __builtin_elementwise_max(v0, zero8);
                half8v v1 = a1 + bc1;
                v1 = __builtin_elementwise_fma(w1b, n8, v1);
                v1 = __builtin_elementwise_fma(w2b, p8, v1);
                half8v af1 = __builtin_elementwise_max(v1, zero8);
                half4v vt = at + bct;
                vt = __builtin_elementwise_fma(w1t, n4, vt);
                vt = __builtin_elementwise_fma(w2t, p4, vt);
                half4v af2 = __builtin_elementwise_max(vt, zero4h);

                // ---- phase B: D[ch][edge] = We2^T @ m1^T ----
                f32x4 acc[5] = {};
                #pragma unroll
                for (int nt = 0; nt < 5; ++nt)
                    acc[nt] = __builtin_amdgcn_mfma_f32_16x16x32_f16(Wf[0][nt], af0, acc[nt], 0, 0, 0);
                #pragma unroll
                for (int nt = 0; nt < 5; ++nt)
                    acc[nt] = __builtin_amdgcn_mfma_f32_16x16x32_f16(Wf[1][nt], af1, acc[nt], 0, 0, 0);
                #pragma unroll
                for (int nt = 0; nt < 5; ++nt)
                    acc[nt] = __builtin_amdgcn_mfma_f32_16x16x16f16(Wf2[nt], af2, acc[nt], 0, 0, 0);

                // ---- phase C: two independent dot chains ----
                f32x2 wdA = {0.f, 0.f}, wdB = {0.f, 0.f};
                #pragma unroll
                for (int nt = 0; nt < 5; ++nt) {
                    f32x4 m2q = __builtin_elementwise_max(acc[nt], zero4);
                    acc[nt] = m2q;
                    f32x2 e0 = {m2q[0], m2q[0]};
                    f32x2 e1 = {m2q[1], m2q[1]};
                    f32x2 e2 = {m2q[2], m2q[2]};
                    f32x2 e3 = {m2q[3], m2q[3]};
                    wdA = __builtin_elementwise_fma(e0, WmWx[nt][0], wdA);
                    wdB = __builtin_elementwise_fma(e1, WmWx[nt][1], wdB);
                    wdA = __builtin_elementwise_fma(e2, WmWx[nt][2], wdA);
                    wdB = __builtin_elementwise_fma(e3, WmWx[nt][3], wdB);
                }
                f32x2 wdpd = wdA + wdB;
                {
                    f32x2 sx;
                    sx[0] = __shfl_xor(wdpd[0], 16, 64);
                    sx[1] = __shfl_xor(wdpd[1], 16, 64);
                    wdpd += sx;
                    sx[0] = __shfl_xor(wdpd[0], 32, 64);
                    sx[1] = __shfl_xor(wdpd[1], 32, 64);
                    wdpd += sx;
                }
                float w_ = __builtin_amdgcn_rcpf(1.f + __expf(-(wdpd[0] + bm0)));
                f32x4 w4 = {w_, w_, w_, w_};
                #pragma unroll
                for (int nt = 0; nt < 5; ++nt)
                    wmacc[nt] = __builtin_elementwise_fma(w4, acc[nt], wmacc[nt]);
                f32x4 pd4 = {wdpd[1], wdpd[1], wdpd[1], wdpd[1]};
                xacc = __builtin_elementwise_fma(pd4, xjv, xacc);

                bc0 = nbc0; bc1 = nbc1; bct = nbct;
            } // s
        } // q

        // ---- finalize: sum across the 16 edge-lanes; stash wm in LDS ----
        #pragma unroll
        for (int nt = 0; nt < 5; ++nt)
            #pragma unroll
            for (int r = 0; r < 4; ++r)
                wmacc[nt][r] = red16(wmacc[nt][r]);
        #pragma unroll
        for (int q = 0; q < 4; ++q) xacc[q] = red16(xacc[q]);

        if (c16 == 0) {
            #pragma unroll
            for (int nt = 0; nt < 5; ++nt)
                #pragma unroll
                for (int r = 0; r < 4; ++r) {
                    int ch = nt * 16 + 4 * g + r;
                    if (ch < C_) wm_s[rowl][ch] = wmacc[nt][r];
                }
        }
        if (l == 0) {
            f32x4 xo = xi + 0.005f * (1.0f / 128.f) * xacc;
            *(f32x4*)&xout[node_i * 4] = xo;
        }
    } // ii

    __syncthreads();   // all waves' wm rows visible

    // ---- fused node MLP, split across all 4 waves by nt ----
    {
        const int row = c16 & 7;                    // 8 rows duplicated to 16
        const float* hrow = h + (m0row + row) * C_;
        const int ntA = wv;                          // wave w owns nt=w
        const bool two = (wv == 3);                  // wave 3 also owns nt=4

        // GEMM1: [h|wm|1] (K=160) @ Wh1(+bh1 row 144), this wave's nt only
        half8v a[5];
        #pragma unroll
        for (int kt = 0; kt < 5; ++kt) {
            int k = kt * 32 + g * 8;
            half8v v = {};
            if (k < C_) v = cvt8(hrow + k);
            else if (k < 144) v = cvt8(&wm_s[row][k - C_]);
            else if (k == 144) v[0] = (_Float16)1.0f;
            a[kt] = v;
        }
        f32x4 acc1a = {}, acc1b = {};
        #pragma unroll
        for (int kt = 0; kt < 5; ++kt) {
            acc1a = __builtin_amdgcn_mfma_f32_16x16x32_f16(
                a[kt], frags[FRAG_WH1 + (kt * 5 + ntA) * 64 + l], acc1a, 0, 0, 0);
            if (two)
                acc1b = __builtin_amdgcn_mfma_f32_16x16x32_f16(
                    a[kt], frags[FRAG_WH1 + (kt * 5 + 4) * 64 + l], acc1b, 0, 0, 0);
        }
        // relu -> shared transpose buffer (each wave its own columns)
        #pragma unroll
        for (int r = 0; r < 4; ++r)
            g_s[4 * g + r][ntA * 16 + c16] = (_Float16)fmaxf(acc1a[r], 0.f);
        if (two) {
            #pragma unroll
            for (int r = 0; r < 4; ++r)
                g_s[4 * g + r][64 + c16] = (_Float16)fmaxf(acc1b[r], 0.f);
        }
        __syncthreads();   // full g rows visible to all waves

        half8v b0 = *(const half8v*)&g_s[c16][g * 8];
        half8v b1 = *(const half8v*)&g_s[c16][32 + g * 8];
        half8v b2 = {};
        if (g == 0) b2 = *(const half8v*)&g_s[c16][64];
        else if (g == 1) b2[0] = (_Float16)1.0f;   // bh2 bias row k=72

        // GEMM2: g (K=96) @ Wh2(+bh2 row 72), this wave's nt only
        f32x4 acc2a = {}, acc2b = {};
        #pragma unroll
        for (int kt = 0; kt < 3; ++kt) {
            half8v aa = (kt == 0) ? b0 : (kt == 1 ? b1 : b2);
            acc2a = __builtin_amdgcn_mfma_f32_16x16x32_f16(
                aa, frags[FRAG_WH2 + (kt * 5 + ntA) * 64 + l], acc2a, 0, 0, 0);
            if (two)
                acc2b = __builtin_amdgcn_mfma_f32_16x16x32_f16(
                    aa, frags[FRAG_WH2 + (kt * 5 + 4) * 64 + l], acc2b, 0, 0, 0);
        }
        // store rows 0..7 (g<2 covers D rows 0..7); cols = this wave's nt
        if (g < 2) {
            int n = ntA * 16 + c16;   // nt 0..3 -> cols 0..63, all valid
            #pragma unroll
            for (int r = 0; r < 4; ++r) {
                int rw = m0row + 4 * g + r;
                hout[rw * C_ + n] = h[rw * C_ + n] + acc2a[r];
            }
            if (two && c16 < 8) {     // nt=4 -> cols 64..71
                int n2 = 64 + c16;
                #pragma unroll
                for (int r = 0; r < 4; ++r) {
                    int rw = m0row + 4 * g + r;
                    hout[rw * C_ + n2] = h[rw * C_ + n2] + acc2b[r];
                }
            }
        }
    }
}

extern "C" void kernel_launch(void* const* d_in, const int* in_sizes, int n_in,
                              void* d_out, int out_size, void* d_ws, size_t ws_size,
                              hipStream_t stream) {
    const float* x   = (const float*)d_in[0];
    const float* h   = (const float*)d_in[1];
    const float* We1 = (const float*)d_in[2];
    const float* be1 = (const float*)d_in[3];
    const float* We2 = (const float*)d_in[4];
    const float* be2 = (const float*)d_in[5];
    const float* Wm  = (const float*)d_in[6];
    const float* bm  = (const float*)d_in[7];
    const float* Wh1 = (const float*)d_in[8];
    const float* bh1 = (const float*)d_in[9];
    const float* Wh2 = (const float*)d_in[10];
    const float* bh2 = (const float*)d_in[11];
    const float* Wx  = (const float*)d_in[12];

    const int NNODE = B_ * P_;                        // 8192
    _Float16* Ah  = (_Float16*)d_ws;                  // [8192][80] f16
    half8v* Bcf   = (half8v*)(Ah + NNODE * PADC);     // 64*8*2*64 half8v = 1 MB
    half4v* Bcft  = (half4v*)(Bcf + B_ * 8 * 2 * 64); // 64*8*64 half4v = 256 KB
    half8v* frags = (half8v*)(Bcft + B_ * 8 * 64);    // 85 frags + tail + w12p + wmwxp

    float* hout = (float*)d_out;                      // [8192][72]
    float* xout = hout + NNODE * C_;                  // [8192][4]

    setup_kernel<<<NFRAG + 6, 64, 0, stream>>>(We1, be1, We2, be2, Wh1, bh1, Wh2, bh2,
                                               Wm, Wx, frags);
    pre_kernel<<<NNODE / 16 * 2, 64, 0, stream>>>(h, frags, Ah, Bcf, Bcft);
    edge_kernel<<<B_ * 16, 256, 0, stream>>>(x, h, Ah, Bcf, Bcft, frags, bm, hout, xout);
}

// Round 18
// 52.123 us; speedup vs baseline: 1.0361x; 1.0361x over previous
//
#include <hip/hip_runtime.h>
#include <hip/hip_bf16.h>
#include <math.h>

#define B_ 64
#define P_ 128
#define C_ 72
#define PADC 80    // f16 global row stride for Ah
#define IT 8       // i-rows per edge block (2 per wave, ii-outer)

typedef __attribute__((ext_vector_type(8))) _Float16 half8v;
typedef __attribute__((ext_vector_type(4))) _Float16 half4v;
typedef __attribute__((ext_vector_type(4))) float f32x4;
typedef __attribute__((ext_vector_type(2))) float f32x2;

// precomputed weight-fragment table (units: half8v, 64 per fragment)
#define FRAG_WE2  0          // We2 kt=0,1 (K32), 15 frag slots
#define FRAG_WE1A (15 * 64)  // We1 rows 0..71, 15 frags
#define FRAG_WE1B (30 * 64)  // We1 rows 72..143 (+be1 @k=72), 15 frags
#define FRAG_WH1  (45 * 64)  // Wh1 (+bh1 @k=144), 25 frags
#define FRAG_WH2  (70 * 64)  // Wh2 (+bh2 @k=72), 15 frags
#define NFRAG 85             // + 5 K16-tail frags + w12p + wmwxp appended

__device__ __forceinline__ float psi_f(float v) {
    float a = fabsf(v);
    return copysignf(__logf(1.0f + a), v);
}
template <int CTRL>
__device__ __forceinline__ float dpp_add(float v) {
    int s = __builtin_amdgcn_update_dpp(0, __builtin_bit_cast(int, v), CTRL, 0xF, 0xF, true);
    return v + __builtin_bit_cast(float, s);
}
// full sum across each 16-lane group (fixed tree -> deterministic)
__device__ __forceinline__ float red16(float v) {
    v = dpp_add<0xB1>(v);    // quad_perm(1,0,3,2)
    v = dpp_add<0x4E>(v);    // quad_perm(2,3,0,1)
    v = dpp_add<0x141>(v);   // row_half_mirror
    v = dpp_add<0x140>(v);   // row_mirror
    return v;
}
__device__ __forceinline__ half8v cvt8(const float* p) {
    f32x4 a = *(const f32x4*)p;
    f32x4 b = *(const f32x4*)(p + 4);
    half8v r = {(_Float16)a[0], (_Float16)a[1], (_Float16)a[2], (_Float16)a[3],
                (_Float16)b[0], (_Float16)b[1], (_Float16)b[2], (_Float16)b[3]};
    return r;
}

// ---------------- Kernel 0: build all weight fragments ------------------
__global__ __launch_bounds__(64) void setup_kernel(
    const float* __restrict__ We1, const float* __restrict__ be1,
    const float* __restrict__ We2, const float* __restrict__ be2,
    const float* __restrict__ Wh1, const float* __restrict__ bh1,
    const float* __restrict__ Wh2, const float* __restrict__ bh2,
    const float* __restrict__ Wm, const float* __restrict__ Wx,
    half8v* __restrict__ frags)
{
    const int bid = blockIdx.x;
    const int l = threadIdx.x;
    const int c16 = l & 15, g = l >> 4;

    if (bid == NFRAG + 5) {
        // padded w144/w145 table: w12p[2][80], zeros beyond col 71
        _Float16* w12p = (_Float16*)((half4v*)(frags + NFRAG * 64) + 5 * 64);
        for (int i = l; i < 160; i += 64) {
            int s = i / 80, c = i - s * 80;
            w12p[i] = (c < C_) ? (_Float16)We1[(144 + s) * C_ + c] : (_Float16)0.f;
        }
        // packed (Wm, Wx) pair table, padded to 80
        f32x2* wmwxp = (f32x2*)(w12p + 160);
        for (int idx = l; idx < 80; idx += 64) {
            f32x2 v;
            v[0] = (idx < C_) ? Wm[idx] : 0.f;
            v[1] = (idx < C_) ? Wx[idx] : 0.f;
            wmwxp[idx] = v;
        }
        return;
    }
    if (bid >= NFRAG) {
        // K16 tail frags for edge We2: k = 64 + 4g + jj, bias(be2) at k=72
        half4v* tail = (half4v*)(frags + NFRAG * 64);
        const int nt = bid - NFRAG;
        const int n = nt * 16 + c16;
        half4v f = {};
        if (n < C_) {
            #pragma unroll
            for (int jj = 0; jj < 4; ++jj) {
                int k = 64 + 4 * g + jj;
                float w = 0.f;
                if (k < C_) w = We2[k * C_ + n];
                else if (k == C_) w = be2[n];
                f[jj] = (_Float16)w;
            }
        }
        tail[nt * 64 + l] = f;
        return;
    }

    const float* W;
    const float* bias;
    int kmax, rel;
    if (bid < 15)      { W = We2;            bias = be2;     kmax = 72;  rel = bid; }
    else if (bid < 30) { W = We1;            bias = nullptr; kmax = 72;  rel = bid - 15; }
    else if (bid < 45) { W = We1 + 72 * C_;  bias = be1;     kmax = 72;  rel = bid - 30; }
    else if (bid < 70) { W = Wh1;            bias = bh1;     kmax = 144; rel = bid - 45; }
    else               { W = Wh2;            bias = bh2;     kmax = 72;  rel = bid - 70; }
    const int kt = rel / 5, nt = rel - 5 * kt;
    const int n = nt * 16 + c16;

    half8v f = {};
    if (n < C_) {
        #pragma unroll
        for (int jj = 0; jj < 8; ++jj) {
            int k = kt * 32 + g * 8 + jj;
            float w = 0.f;
            if (k < kmax) w = W[k * C_ + n];
            else if (k == kmax && bias) w = bias[n];
            f[jj] = (_Float16)w;
        }
    }
    frags[bid * 64 + l] = f;
}

// ---------------- Kernel 1: pre (MFMA) ----------------------------------
// sel=0: A rows (row layout, bias 1.0 baked at col 72).  sel=1: Bc frags.
__global__ __launch_bounds__(64) void pre_kernel(
    const float* __restrict__ h, const half8v* __restrict__ frags,
    _Float16* __restrict__ Ah, half8v* __restrict__ Bcf,
    half4v* __restrict__ Bcft)
{
    __shared__ _Float16 T[16][88];
    const int l = threadIdx.x, c16 = l & 15, g = l >> 4;
    const int sel = blockIdx.x & 1;
    const int m0 = (blockIdx.x >> 1) * 16;

    const float* hrow = h + (m0 + c16) * C_;
    half8v a0 = cvt8(hrow + g * 8);
    half8v a1 = cvt8(hrow + 32 + g * 8);
    half8v a2 = {};
    if (g == 0) a2 = cvt8(hrow + 64);
    else if (g == 1) a2[0] = (_Float16)1.0f;   // bias row k=72

    const half8v* F = frags + (sel ? FRAG_WE1B : FRAG_WE1A);
    f32x4 acc[5] = {};
    #pragma unroll
    for (int kt = 0; kt < 3; ++kt) {
        half8v a = (kt == 0) ? a0 : (kt == 1 ? a1 : a2);
        #pragma unroll
        for (int nt = 0; nt < 5; ++nt)
            acc[nt] = __builtin_amdgcn_mfma_f32_16x16x32_f16(a, F[(kt * 5 + nt) * 64 + l], acc[nt], 0, 0, 0);
    }

    if (sel == 0) {
        #pragma unroll
        for (int nt = 0; nt < 5; ++nt) {
            int n = nt * 16 + c16;
            if (n < C_) {
                #pragma unroll
                for (int r = 0; r < 4; ++r)
                    Ah[(m0 + 4 * g + r) * PADC + n] = (_Float16)acc[nt][r];
            }
        }
        if (l < 16) {   // bake be2-bias marker: col 72 = 1.0, 73..79 = 0
            half4v one = {(_Float16)1.0f, (_Float16)0.f, (_Float16)0.f, (_Float16)0.f};
            half4v z = {};
            *(half4v*)&Ah[(m0 + l) * PADC + 72] = one;
            *(half4v*)&Ah[(m0 + l) * PADC + 76] = z;
        }
    } else {
        // D layout -> LDS -> B-fragment layout
        #pragma unroll
        for (int nt = 0; nt < 5; ++nt) {
            int n = nt * 16 + c16;
            if (n < C_) {
                #pragma unroll
                for (int r = 0; r < 4; ++r)
                    T[4 * g + r][n] = (_Float16)acc[nt][r];
            }
        }
        {   // zero pad cols 72..87
            int zr = l >> 2, zc = 72 + (l & 3) * 4;
            half4v z = {};
            *(half4v*)&T[zr][zc] = z;
        }
        __syncthreads();
        const int bb = m0 >> 7, jt = (m0 >> 4) & 7;
        half8v f0 = *(const half8v*)&T[c16][g * 8];
        half8v f1 = *(const half8v*)&T[c16][32 + g * 8];
        half4v ft = *(const half4v*)&T[c16][64 + g * 4];
        Bcf[((bb * 8 + jt) * 2 + 0) * 64 + l] = f0;
        Bcf[((bb * 8 + jt) * 2 + 1) * 64 + l] = f1;
        Bcft[(bb * 8 + jt) * 64 + l] = ft;
    }
}

// ---------------- Kernel 2: edge MLP + fused node MLP (wave-0 tail) -----
__global__ __launch_bounds__(256, 2) void edge_kernel(
    const float* __restrict__ x, const float* __restrict__ h,
    const _Float16* __restrict__ Ah,
    const half8v* __restrict__ Bcf, const half4v* __restrict__ Bcft,
    const half8v* __restrict__ frags,
    const float* __restrict__ bm,
    float* __restrict__ hout, float* __restrict__ xout)
{
    __shared__ float wm_s[IT][80];          // this block's wm rows (f32)
    __shared__ _Float16 g_s[16][88];        // node GEMM1 transpose buffer

    const int b  = blockIdx.x >> 4;
    const int it = blockIdx.x & 15;
    const int t  = threadIdx.x;
    const int wv = t >> 6;
    const int l  = t & 63;
    const int c16 = l & 15;
    const int g   = l >> 4;

    // ---- We2 fragments: 2x K32 + 1x K16 tail ----
    half8v Wf[2][5];
    #pragma unroll
    for (int kt = 0; kt < 2; ++kt)
        #pragma unroll
        for (int nt = 0; nt < 5; ++nt)
            Wf[kt][nt] = frags[FRAG_WE2 + (kt * 5 + nt) * 64 + l];
    half4v Wf2[5];
    const half4v* tail = (const half4v*)(frags + NFRAG * 64);
    #pragma unroll
    for (int nt = 0; nt < 5; ++nt)
        Wf2[nt] = tail[nt * 64 + l];

    // padded w144/w145 table
    const _Float16* w12p = (const _Float16*)(tail + 5 * 64);
    half8v w1a = *(const half8v*)&w12p[g * 8];
    half8v w1b = *(const half8v*)&w12p[32 + g * 8];
    half4v w1t = *(const half4v*)&w12p[64 + g * 4];
    half8v w2a = *(const half8v*)&w12p[80 + g * 8];
    half8v w2b = *(const half8v*)&w12p[80 + 32 + g * 8];
    half4v w2t = *(const half4v*)&w12p[80 + 64 + g * 4];

    // packed (Wm,Wx) pairs: 10 vector loads instead of 40 scalar
    const f32x2* wmwxp = (const f32x2*)(w12p + 160);
    f32x2 WmWx[5][4];
    #pragma unroll
    for (int nt = 0; nt < 5; ++nt) {
        f32x4 p0 = *(const f32x4*)&wmwxp[nt * 16 + 4 * g];
        f32x4 p1 = *(const f32x4*)&wmwxp[nt * 16 + 4 * g + 2];
        WmWx[nt][0][0] = p0[0]; WmWx[nt][0][1] = p0[1];
        WmWx[nt][1][0] = p0[2]; WmWx[nt][1][1] = p0[3];
        WmWx[nt][2][0] = p1[0]; WmWx[nt][2][1] = p1[1];
        WmWx[nt][3][0] = p1[2]; WmWx[nt][3][1] = p1[3];
    }
    const float bm0 = bm[0];
    const f32x4 zero4 = {0.f, 0.f, 0.f, 0.f};

    const half8v* Bb = Bcf + (size_t)(b * 8) * 2 * 64;
    const half4v* Bt = Bcft + (size_t)(b * 8) * 64;
    const float*  xb = x + b * P_ * 4;
    const int c16_4 = c16 << 2;
    const int m0row = b * P_ + it * IT;

    #pragma unroll 1
    for (int ii = 0; ii < 2; ++ii) {
        const int rowl = wv * 2 + ii;
        const int node_i = m0row + rowl;
        const f32x4 xi = *(const f32x4*)&x[node_i * 4];
        const _Float16* Arow = Ah + node_i * PADC;
        half8v a0 = *(const half8v*)&Arow[g * 8];
        half8v a1 = *(const half8v*)&Arow[32 + g * 8];
        half4v at = *(const half4v*)&Arow[64 + g * 4];   // g=2 carries baked bias

        // Bc prefetch, 1-deep
        half8v bc0 = Bb[l];
        half8v bc1 = Bb[64 + l];
        half4v bct = Bt[l];

        f32x4 wmacc[5] = {};
        f32x4 xacc = {0.f, 0.f, 0.f, 0.f};

        #pragma unroll 1
        for (int q = 0; q < 2; ++q) {
            // ---- 64-edge geometry + psi, computed ONCE per 4 tiles ----
            f32x4 xjq = *(const f32x4*)&xb[(q * 64 + l) * 4];
            float d0 = xi[0] - xjq[0], d1 = xi[1] - xjq[1];
            float d2 = xi[2] - xjq[2], d3 = xi[3] - xjq[3];
            float nn = d0 * d0 - d1 * d1 - d2 * d2 - d3 * d3;
            float pp = xi[0] * xjq[0] - xi[1] * xjq[1] - xi[2] * xjq[2] - xi[3] * xjq[3];
            unsigned geo =
                (unsigned)__builtin_bit_cast(unsigned short, (_Float16)psi_f(nn)) |
                ((unsigned)__builtin_bit_cast(unsigned short, (_Float16)psi_f(pp)) << 16);
            int geo0 = __builtin_amdgcn_ds_bpermute(c16_4,       (int)geo);
            int geo1 = __builtin_amdgcn_ds_bpermute(c16_4 + 64,  (int)geo);
            int geo2 = __builtin_amdgcn_ds_bpermute(c16_4 + 128, (int)geo);
            int geo3 = __builtin_amdgcn_ds_bpermute(c16_4 + 192, (int)geo);

            #pragma unroll
            for (int s = 0; s < 4; ++s) {
                const int jt = q * 4 + s;
                const int njt = (jt + 1) & 7;
                half8v nbc0 = Bb[(njt * 2) * 64 + l];
                half8v nbc1 = Bb[(njt * 2 + 1) * 64 + l];
                half4v nbct = Bt[njt * 64 + l];
                f32x4 xjv = *(const f32x4*)&xb[(jt * 16 + c16) * 4];

                int geos = (s == 0) ? geo0 : (s == 1) ? geo1 : (s == 2) ? geo2 : geo3;
                _Float16 nh = __builtin_bit_cast(_Float16, (unsigned short)((unsigned)geos & 0xFFFFu));
                _Float16 ph = __builtin_bit_cast(_Float16, (unsigned short)((unsigned)geos >> 16));
                half8v n8 = {nh, nh, nh, nh, nh, nh, nh, nh};
                half8v p8 = {ph, ph, ph, ph, ph, ph, ph, ph};
                half4v n4 = {nh, nh, nh, nh};
                half4v p4 = {ph, ph, ph, ph};
                half8v zero8 = {};
                half4v zero4h = {};

                // ---- phase A: m1^T fragments (branch-free tail) ----
                half8v v0 = a0 + bc0;
                v0 = __builtin_elementwise_fma(w1a, n8, v0);
                v0 = __builtin_elementwise_fma(w2a, p8, v0);
                half8v af0 = __builtin_elementwise_max(v0, zero8);
                half8v v1 = a1 + bc1;
                v1 = __builtin_elementwise_fma(w1b, n8, v1);
                v1 = __builtin_elementwise_fma(w2b, p8, v1);
                half8v af1 = __builtin_elementwise_max(v1, zero8);
                half4v vt = at + bct;
                vt = __builtin_elementwise_fma(w1t, n4, vt);
                vt = __builtin_elementwise_fma(w2t, p4, vt);
                half4v af2 = __builtin_elementwise_max(vt, zero4h);

                // ---- phase B: D[ch][edge] = We2^T @ m1^T ----
                f32x4 acc[5] = {};
                #pragma unroll
                for (int nt = 0; nt < 5; ++nt)
                    acc[nt] = __builtin_amdgcn_mfma_f32_16x16x32_f16(Wf[0][nt], af0, acc[nt], 0, 0, 0);
                #pragma unroll
                for (int nt = 0; nt < 5; ++nt)
                    acc[nt] = __builtin_amdgcn_mfma_f32_16x16x32_f16(Wf[1][nt], af1, acc[nt], 0, 0, 0);
                #pragma unroll
                for (int nt = 0; nt < 5; ++nt)
                    acc[nt] = __builtin_amdgcn_mfma_f32_16x16x16f16(Wf2[nt], af2, acc[nt], 0, 0, 0);

                // ---- phase C: two independent dot chains ----
                f32x2 wdA = {0.f, 0.f}, wdB = {0.f, 0.f};
                #pragma unroll
                for (int nt = 0; nt < 5; ++nt) {
                    f32x4 m2q = __builtin_elementwise_max(acc[nt], zero4);
                    acc[nt] = m2q;
                    f32x2 e0 = {m2q[0], m2q[0]};
                    f32x2 e1 = {m2q[1], m2q[1]};
                    f32x2 e2 = {m2q[2], m2q[2]};
                    f32x2 e3 = {m2q[3], m2q[3]};
                    wdA = __builtin_elementwise_fma(e0, WmWx[nt][0], wdA);
                    wdB = __builtin_elementwise_fma(e1, WmWx[nt][1], wdB);
                    wdA = __builtin_elementwise_fma(e2, WmWx[nt][2], wdA);
                    wdB = __builtin_elementwise_fma(e3, WmWx[nt][3], wdB);
                }
                f32x2 wdpd = wdA + wdB;
                {
                    f32x2 sx;
                    sx[0] = __shfl_xor(wdpd[0], 16, 64);
                    sx[1] = __shfl_xor(wdpd[1], 16, 64);
                    wdpd += sx;
                    sx[0] = __shfl_xor(wdpd[0], 32, 64);
                    sx[1] = __shfl_xor(wdpd[1], 32, 64);
                    wdpd += sx;
                }
                float w_ = __builtin_amdgcn_rcpf(1.f + __expf(-(wdpd[0] + bm0)));
                f32x4 w4 = {w_, w_, w_, w_};
                #pragma unroll
                for (int nt = 0; nt < 5; ++nt)
                    wmacc[nt] = __builtin_elementwise_fma(w4, acc[nt], wmacc[nt]);
                f32x4 pd4 = {wdpd[1], wdpd[1], wdpd[1], wdpd[1]};
                xacc = __builtin_elementwise_fma(pd4, xjv, xacc);

                bc0 = nbc0; bc1 = nbc1; bct = nbct;
            } // s
        } // q

        // ---- finalize: sum across the 16 edge-lanes; stash wm in LDS ----
        #pragma unroll
        for (int nt = 0; nt < 5; ++nt)
            #pragma unroll
            for (int r = 0; r < 4; ++r)
                wmacc[nt][r] = red16(wmacc[nt][r]);
        #pragma unroll
        for (int q = 0; q < 4; ++q) xacc[q] = red16(xacc[q]);

        if (c16 == 0) {
            #pragma unroll
            for (int nt = 0; nt < 5; ++nt)
                #pragma unroll
                for (int r = 0; r < 4; ++r) {
                    int ch = nt * 16 + 4 * g + r;
                    if (ch < C_) wm_s[rowl][ch] = wmacc[nt][r];
                }
        }
        if (l == 0) {
            f32x4 xo = xi + 0.005f * (1.0f / 128.f) * xacc;
            *(f32x4*)&xout[node_i * 4] = xo;
        }
    } // ii

    __syncthreads();   // all waves' wm rows visible

    // ---- fused node MLP (wave 0 only; 8 rows duplicated to 16) ----
    if (wv != 0) return;
    {
        const int row = c16 & 7;                    // duplicate 8 rows
        const float* hrow = h + (m0row + row) * C_;

        // GEMM1: [h|wm|1] (K=160) @ Wh1(+bh1 row 144)
        half8v a[5];
        #pragma unroll
        for (int kt = 0; kt < 5; ++kt) {
            int k = kt * 32 + g * 8;
            half8v v = {};
            if (k < C_) v = cvt8(hrow + k);
            else if (k < 144) v = cvt8(&wm_s[row][k - C_]);
            else if (k == 144) v[0] = (_Float16)1.0f;
            a[kt] = v;
        }
        f32x4 acc1[5] = {};
        #pragma unroll
        for (int kt = 0; kt < 5; ++kt)
            #pragma unroll
            for (int nt = 0; nt < 5; ++nt)
                acc1[nt] = __builtin_amdgcn_mfma_f32_16x16x32_f16(
                    a[kt], frags[FRAG_WH1 + (kt * 5 + nt) * 64 + l], acc1[nt], 0, 0, 0);

        // relu -> wave-local LDS transpose (D layout -> A-fragment layout)
        #pragma unroll
        for (int nt = 0; nt < 5; ++nt) {
            int n = nt * 16 + c16;
            #pragma unroll
            for (int r = 0; r < 4; ++r)
                g_s[4 * g + r][n] = (_Float16)fmaxf(acc1[nt][r], 0.f);
        }
        // wave-local RAW: compiler inserts lgkmcnt wait (no barrier needed)
        half8v b0 = *(const half8v*)&g_s[c16][g * 8];
        half8v b1 = *(const half8v*)&g_s[c16][32 + g * 8];
        half8v b2 = {};
        if (g == 0) b2 = *(const half8v*)&g_s[c16][64];
        else if (g == 1) b2[0] = (_Float16)1.0f;   // bh2 bias row k=72

        // GEMM2: g (K=96) @ Wh2(+bh2 row 72)
        f32x4 acc2[5] = {};
        #pragma unroll
        for (int kt = 0; kt < 3; ++kt) {
            half8v aa = (kt == 0) ? b0 : (kt == 1 ? b1 : b2);
            #pragma unroll
            for (int nt = 0; nt < 5; ++nt)
                acc2[nt] = __builtin_amdgcn_mfma_f32_16x16x32_f16(
                    aa, frags[FRAG_WH2 + (kt * 5 + nt) * 64 + l], acc2[nt], 0, 0, 0);
        }
        // store rows 0..7 only (g<2 covers D rows 0..7)
        if (g < 2) {
            #pragma unroll
            for (int nt = 0; nt < 5; ++nt) {
                int n = nt * 16 + c16;
                if (n < C_) {
                    #pragma unroll
                    for (int r = 0; r < 4; ++r) {
                        int rw = m0row + 4 * g + r;
                        hout[rw * C_ + n] = h[rw * C_ + n] + acc2[r >= 0 ? nt : nt][r];
                    }
                }
            }
        }
    }
}

extern "C" void kernel_launch(void* const* d_in, const int* in_sizes, int n_in,
                              void* d_out, int out_size, void* d_ws, size_t ws_size,
                              hipStream_t stream) {
    const float* x   = (const float*)d_in[0];
    const float* h   = (const float*)d_in[1];
    const float* We1 = (const float*)d_in[2];
    const float* be1 = (const float*)d_in[3];
    const float* We2 = (const float*)d_in[4];
    const float* be2 = (const float*)d_in[5];
    const float* Wm  = (const float*)d_in[6];
    const float* bm  = (const float*)d_in[7];
    const float* Wh1 = (const float*)d_in[8];
    const float* bh1 = (const float*)d_in[9];
    const float* Wh2 = (const float*)d_in[10];
    const float* bh2 = (const float*)d_in[11];
    const float* Wx  = (const float*)d_in[12];

    const int NNODE = B_ * P_;                        // 8192
    _Float16* Ah  = (_Float16*)d_ws;                  // [8192][80] f16
    half8v* Bcf   = (half8v*)(Ah + NNODE * PADC);     // 64*8*2*64 half8v = 1 MB
    half4v* Bcft  = (half4v*)(Bcf + B_ * 8 * 2 * 64); // 64*8*64 half4v = 256 KB
    half8v* frags = (half8v*)(Bcft + B_ * 8 * 64);    // 85 frags + tail + w12p + wmwxp

    float* hout = (float*)d_out;                      // [8192][72]
    float* xout = hout + NNODE * C_;                  // [8192][4]

    setup_kernel<<<NFRAG + 6, 64, 0, stream>>>(We1, be1, We2, be2, Wh1, bh1, Wh2, bh2,
                                               Wm, Wx, frags);
    pre_kernel<<<NNODE / 16 * 2, 64, 0, stream>>>(h, frags, Ah, Bcf, Bcft);
    edge_kernel<<<B_ * 16, 256, 0, stream>>>(x, h, Ah, Bcf, Bcft, frags, bm, hout, xout);
}